// Round 16
// baseline (1830.976 us; speedup 1.0000x reference)
//
#include <hip/hip_runtime.h>
#include <math.h>

#define TPB   256
#define SL    16
#define SEGS  65536           // 16-sample segments per row
#define PAIRS 32768
#define TLEN  1048576
#define MOFF  4065            // 65047 / 16
#define ROFF  7               // 65047 % 16
#define NEMA  4               // 0 short/pred, 1 short/targ, 2 long/pred, 3 long/targ
#define NTIL  1024            // 64-seg tiles per row
#define PPR   512             // P-items per row (128 segs each)
#define LPR   1024            // L-items per row (64 segs each)

typedef float v4f __attribute__((ext_vector_type(4)));

__device__ __forceinline__ float comp(const float4& v, int m) {
    return m == 0 ? v.x : m == 1 ? v.y : m == 2 ? v.z : v.w;
}

__device__ __forceinline__ float ipowf(float base, int e) {
    float r = 1.0f, p = base;
    while (e) { if (e & 1) r *= p; p *= p; e >>= 1; }
    return r;
}

// P-item: one wave computes per-seg EMA aggregates for 128 consecutive segs
// (2 segs/lane, the proven 16-load asm block) + the two 64-seg tile
// aggregates via half-wave weighted reduce. No LDS, no barriers.
__device__ __forceinline__ void p_item(
    const float* __restrict__ pred, const float* __restrict__ targ,
    float* __restrict__ pB, float* __restrict__ tA,
    int item, int lane, float amS, float amL, float Ac16S, float Ac16L,
    int rows)
{
    const int r = item >> 9;
    const int q = item & (PPR - 1);
    const int p = q * 64 + lane;                 // pair index in row
    const size_t base = (size_t)r * TLEN + (size_t)p * 32;
    const float* P = pred + base;
    const float* T = targ + base;

    v4f u0, u1, u2, u3, u4, u5, u6, u7;
    v4f w0, w1, w2, w3, w4, w5, w6, w7;
    asm volatile(
        "global_load_dwordx4 %[u0], %[pa], off\n\t"
        "global_load_dwordx4 %[u1], %[pa], off offset:16\n\t"
        "global_load_dwordx4 %[u2], %[pa], off offset:32\n\t"
        "global_load_dwordx4 %[u3], %[pa], off offset:48\n\t"
        "global_load_dwordx4 %[u4], %[pa], off offset:64\n\t"
        "global_load_dwordx4 %[u5], %[pa], off offset:80\n\t"
        "global_load_dwordx4 %[u6], %[pa], off offset:96\n\t"
        "global_load_dwordx4 %[u7], %[pa], off offset:112\n\t"
        "global_load_dwordx4 %[w0], %[ta], off\n\t"
        "global_load_dwordx4 %[w1], %[ta], off offset:16\n\t"
        "global_load_dwordx4 %[w2], %[ta], off offset:32\n\t"
        "global_load_dwordx4 %[w3], %[ta], off offset:48\n\t"
        "global_load_dwordx4 %[w4], %[ta], off offset:64\n\t"
        "global_load_dwordx4 %[w5], %[ta], off offset:80\n\t"
        "global_load_dwordx4 %[w6], %[ta], off offset:96\n\t"
        "global_load_dwordx4 %[w7], %[ta], off offset:112\n\t"
        "s_waitcnt vmcnt(0)"
        : [u0] "=&v"(u0), [u1] "=&v"(u1), [u2] "=&v"(u2), [u3] "=&v"(u3),
          [u4] "=&v"(u4), [u5] "=&v"(u5), [u6] "=&v"(u6), [u7] "=&v"(u7),
          [w0] "=&v"(w0), [w1] "=&v"(w1), [w2] "=&v"(w2), [w3] "=&v"(w3),
          [w4] "=&v"(w4), [w5] "=&v"(w5), [w6] "=&v"(w6), [w7] "=&v"(w7)
        : [pa] "v"(P), [ta] "v"(T)
        : "memory");

    float res[NEMA][2];
    #define PQ(Q) { sp = fmaf(amS, sp, Q.x); lp = fmaf(amL, lp, Q.x);         \
                    sp = fmaf(amS, sp, Q.y); lp = fmaf(amL, lp, Q.y);         \
                    sp = fmaf(amS, sp, Q.z); lp = fmaf(amL, lp, Q.z);         \
                    sp = fmaf(amS, sp, Q.w); lp = fmaf(amL, lp, Q.w); }
    #define TQ(Q) { st = fmaf(amS, st, Q.x); lt = fmaf(amL, lt, Q.x);         \
                    st = fmaf(amS, st, Q.y); lt = fmaf(amL, lt, Q.y);         \
                    st = fmaf(amS, st, Q.z); lt = fmaf(amL, lt, Q.z);         \
                    st = fmaf(amS, st, Q.w); lt = fmaf(amL, lt, Q.w); }
    {
        float sp = 0.f, st = 0.f, lp = 0.f, lt = 0.f;
        PQ(u0) PQ(u1) PQ(u2) PQ(u3)
        TQ(w0) TQ(w1) TQ(w2) TQ(w3)
        res[0][0] = sp; res[1][0] = st; res[2][0] = lp; res[3][0] = lt;
    }
    {
        float sp = 0.f, st = 0.f, lp = 0.f, lt = 0.f;
        PQ(u4) PQ(u5) PQ(u6) PQ(u7)
        TQ(w4) TQ(w5) TQ(w6) TQ(w7)
        res[0][1] = sp; res[1][1] = st; res[2][1] = lp; res[3][1] = lt;
    }
    #undef PQ
    #undef TQ
    const size_t plane = (size_t)rows * SEGS;
    const size_t idx = (size_t)r * SEGS + 2 * (size_t)p;
    #pragma unroll
    for (int E = 0; E < NEMA; ++E)
        *(float2*)(pB + E * plane + idx) = make_float2(res[E][0], res[E][1]);

    // tile aggregates: tile = q*2 + (lane>>5); pairAgg weight Ac32^(31-hh)
    const int hh = lane & 31, h2 = lane >> 5;
    const float Ac32S = Ac16S * Ac16S, Ac32L = Ac16L * Ac16L;
    const float wgtS = ipowf(Ac32S, 31 - hh);
    const float wgtL = ipowf(Ac32L, 31 - hh);
    float vals[NEMA];
    vals[0] = fmaf(Ac16S, res[0][0], res[0][1]) * wgtS;
    vals[1] = fmaf(Ac16S, res[1][0], res[1][1]) * wgtS;
    vals[2] = fmaf(Ac16L, res[2][0], res[2][1]) * wgtL;
    vals[3] = fmaf(Ac16L, res[3][0], res[3][1]) * wgtL;
    #pragma unroll
    for (int E = 0; E < NEMA; ++E) {
        float s = vals[E];
        #pragma unroll
        for (int d = 1; d < 32; d <<= 1) s += __shfl_xor(s, d, 64);
        vals[E] = s;
    }
    if (hh == 0) {
        const int tile = q * 2 + h2;
        #pragma unroll
        for (int E = 0; E < NEMA; ++E)
            tA[((size_t)E * rows + r) * NTIL + tile] = vals[E];
    }
}

// Row scan: one wave scans the 4 planes' 1024 tile aggregates -> tC carries.
__device__ __forceinline__ void scan_row(
    const float* __restrict__ tA, float* __restrict__ tC,
    int r, int lane, float AcTS, float AcTL, int rows)
{
    #pragma unroll
    for (int E = 0; E < NEMA; ++E) {
        const float AcT = (E < 2) ? AcTS : AcTL;       // am^1024 per tile
        const float* Av = tA + ((size_t)E * rows + r) * NTIL + (size_t)lane * 16;
        float v[16];
        float B = 0.f;
        #pragma unroll
        for (int m2 = 0; m2 < 16; ++m2) { v[m2] = Av[m2]; B = fmaf(AcT, B, v[m2]); }
        float incl = B, Ad = ipowf(AcT, 16);
        #pragma unroll
        for (int d = 1; d < 64; d <<= 1) {
            float pb = __shfl_up(incl, d, 64);
            if (lane >= d) incl = fmaf(Ad, pb, incl);
            Ad *= Ad;
        }
        float carry = __shfl_up(incl, 1, 64);
        if (lane == 0) carry = 0.f;
        float* co = tC + ((size_t)E * rows + r) * NTIL + (size_t)lane * 16;
        #pragma unroll
        for (int m2 = 0; m2 < 16; ++m2) { co[m2] = carry; carry = fmaf(AcT, carry, v[m2]); }
    }
}

// L-item: one wave = 64 output segs (tile k). Derives all carries wave-locally
// (6-wide shfl scan over pB aggregates + tC tile bases; long carries selected
// across tiles k+63/k+64 via shfl), then runs the verified per-lane loss body.
__device__ __forceinline__ float l_item(
    const float* __restrict__ pred, const float* __restrict__ targ,
    const float* __restrict__ pB, const float* __restrict__ tC,
    int item, int lane, float amS, float amL, float Ac16S, float Ac16L,
    int rows)
{
    const int r = item >> 10;
    const int k = item & (NTIL - 1);
    const int m = k * 64 + lane;
    const int ta0 = (k + 63) & (NTIL - 1);
    const int ta1 = (k + 64) & (NTIL - 1);
    const size_t plane = (size_t)rows * SEGS;
    const size_t rbase = (size_t)r * SEGS;

    float i0 = pB[0 * plane + rbase + m];
    float i1 = pB[1 * plane + rbase + m];
    float i2 = pB[2 * plane + rbase + ta0 * 64 + lane];
    float i3 = pB[3 * plane + rbase + ta0 * 64 + lane];
    float i4 = pB[2 * plane + rbase + ta1 * 64 + lane];
    float i5 = pB[3 * plane + rbase + ta1 * 64 + lane];
    float AdS = Ac16S, AdL = Ac16L;
    #pragma unroll
    for (int d = 1; d < 64; d <<= 1) {
        float p0 = __shfl_up(i0, d, 64), p1 = __shfl_up(i1, d, 64);
        float p2 = __shfl_up(i2, d, 64), p3 = __shfl_up(i3, d, 64);
        float p4 = __shfl_up(i4, d, 64), p5 = __shfl_up(i5, d, 64);
        if (lane >= d) {
            i0 = fmaf(AdS, p0, i0); i1 = fmaf(AdS, p1, i1);
            i2 = fmaf(AdL, p2, i2); i3 = fmaf(AdL, p3, i3);
            i4 = fmaf(AdL, p4, i4); i5 = fmaf(AdL, p5, i5);
        }
        AdS *= AdS; AdL *= AdL;
    }
    float e0 = __shfl_up(i0, 1, 64), e1 = __shfl_up(i1, 1, 64);
    float e2 = __shfl_up(i2, 1, 64), e3 = __shfl_up(i3, 1, 64);
    float e4 = __shfl_up(i4, 1, 64), e5 = __shfl_up(i5, 1, 64);
    if (lane == 0) { e0 = e1 = e2 = e3 = e4 = e5 = 0.f; }
    const float pwS = ipowf(Ac16S, lane), pwL = ipowf(Ac16L, lane);
    const float cSp = fmaf(pwS, tC[((size_t)0 * rows + r) * NTIL + k], e0);
    const float cSt = fmaf(pwS, tC[((size_t)1 * rows + r) * NTIL + k], e1);
    const float c0p = fmaf(pwL, tC[((size_t)2 * rows + r) * NTIL + ta0], e2);
    const float c0t = fmaf(pwL, tC[((size_t)3 * rows + r) * NTIL + ta0], e3);
    const float c1p = fmaf(pwL, tC[((size_t)2 * rows + r) * NTIL + ta1], e4);
    const float c1t = fmaf(pwL, tC[((size_t)3 * rows + r) * NTIL + ta1], e5);
    // seg a = m + 4065; 4065 = 63*64 + 33 -> offset 33+lane in tile ta0/ta1
    float s0p = __shfl(c0p, lane + 33, 64), s1p = __shfl(c1p, lane - 31, 64);
    float s0t = __shfl(c0t, lane + 33, 64), s1t = __shfl(c1t, lane - 31, 64);
    const float cLp = (lane < 31) ? s0p : s1p;
    const float cLt = (lane < 31) ? s0t : s1t;

    // ---- verified per-lane loss body (R10..R15) ----
    const int a = (m + MOFF) & (SEGS - 1);
    const int bseg = (m + MOFF + 1) & (SEGS - 1);
    const float* P = pred + (size_t)r * TLEN;
    const float* T = targ + (size_t)r * TLEN;

    float sp[SL], st[SL];
    {
        const float4* Sp4 = (const float4*)(P + (size_t)m * SL);
        const float4* St4 = (const float4*)(T + (size_t)m * SL);
        float ysp = cSp, yst = cSt;
        #pragma unroll
        for (int qq = 0; qq < SL / 4; ++qq) {
            float4 u = Sp4[qq], v = St4[qq];
            #pragma unroll
            for (int mm = 0; mm < 4; ++mm) {
                ysp = fmaf(amS, ysp, comp(u, mm)); sp[4 * qq + mm] = ysp;
                yst = fmaf(amS, yst, comp(v, mm)); st[4 * qq + mm] = yst;
            }
        }
    }
    float ylp = cLp, ylt = cLt;
    const float4* Ap4 = (const float4*)(P + (size_t)a * SL);
    const float4* At4 = (const float4*)(T + (size_t)a * SL);
    const float4* Bp4 = (const float4*)(P + (size_t)bseg * SL);
    const float4* Bt4 = (const float4*)(T + (size_t)bseg * SL);

    float lsum = 0.f;
    #pragma unroll
    for (int qq = 0; qq < SL / 4; ++qq) {
        float4 u = Ap4[qq], v = At4[qq];
        #pragma unroll
        for (int mm = 0; mm < 4; ++mm) {
            const int e = 4 * qq + mm;
            ylp = fmaf(amL, ylp, comp(u, mm));
            ylt = fmaf(amL, ylt, comp(v, mm));
            if (e >= ROFF) {
                const int i = e - ROFF;
                lsum += fabsf(__logf(__fdividef(sp[i] * ylt, st[i] * ylp)));
            }
        }
    }
    #pragma unroll
    for (int qq = 0; qq < 2; ++qq) {
        float4 u = Bp4[qq], v = Bt4[qq];
        #pragma unroll
        for (int mm = 0; mm < 4; ++mm) {
            const int e = 4 * qq + mm;
            if (e < ROFF) {
                ylp = fmaf(amL, ylp, comp(u, mm));
                ylt = fmaf(amL, ylt, comp(v, mm));
                const int i = e + (SL - ROFF);
                lsum += fabsf(__logf(__fdividef(sp[i] * ylt, st[i] * ylp)));
            }
        }
    }
    return lsum;
}

// Mega-kernel: every wave is an independent work-stealing worker. P-items
// (HBM-latency-bound) and L-items (L2/L3-bound) run on the same CUs
// concurrently -> the two regimes overlap instead of serializing.
// ctrl: [0]=qP, [1]=qL, [2..2+rows)=rowdone, [2+rows..2+2rows)=rowready.
__global__ __launch_bounds__(TPB) void ldr_mega(
    const float* __restrict__ pred, const float* __restrict__ targ,
    float* __restrict__ pB, float* __restrict__ tA, float* __restrict__ tC,
    float* __restrict__ partial, int* __restrict__ ctrl,
    float amS, float amL, float Ac16S, float Ac16L,
    float AcTS, float AcTL, int rows)
{
    const int lane = threadIdx.x & 63;
    const int maxP = rows * PPR;
    const int maxL = rows * LPR;
    int pend = -1;                               // wave-uniform pending L-item

    while (true) {
        if (pend == -1) {                        // eagerly hold one L-item
            int l = 0;
            if (lane == 0) l = atomicAdd(&ctrl[1], 1);
            l = __shfl(l, 0, 64);
            pend = (l < maxL) ? l : -2;
        }
        if (pend >= 0) {
            int f = 0;
            if (lane == 0) f = atomicAdd(&ctrl[2 + rows + (pend >> 10)], 0);
            f = __shfl(f, 0, 64);
            if (f) {
                __threadfence();                 // acquire pB/tC of the row
                float ls = l_item(pred, targ, pB, tC, pend, lane,
                                  amS, amL, Ac16S, Ac16L, rows);
                #pragma unroll
                for (int d = 32; d > 0; d >>= 1) ls += __shfl_xor(ls, d, 64);
                if (lane == 0) partial[pend] = ls;
                pend = -1;
                continue;
            }
        }
        int p = 0;
        if (lane == 0) p = atomicAdd(&ctrl[0], 1);
        p = __shfl(p, 0, 64);
        if (p < maxP) {
            p_item(pred, targ, pB, tA, p, lane, amS, amL, Ac16S, Ac16L, rows);
            __threadfence();                     // release pB/tA
            const int r = p >> 9;
            int c = 0;
            if (lane == 0) c = atomicAdd(&ctrl[2 + r], 1);
            c = __shfl(c, 0, 64);
            if (c == PPR - 1) {                  // last P-item of row: scan it
                __threadfence();                 // acquire other waves' tA
                scan_row(tA, tC, r, lane, AcTS, AcTL, rows);
                __threadfence();                 // release tC
                if (lane == 0) atomicExch(&ctrl[2 + rows + r], 1);
            }
            continue;
        }
        if (pend >= 0) { __builtin_amdgcn_s_sleep(16); continue; }
        break;                                   // both queues drained
    }
}

__global__ void ldr_finalize(const float* __restrict__ partial, int nparts,
                             float* __restrict__ out, double inv_n)
{
    __shared__ double sd[256];
    double s = 0.0;
    for (int i = threadIdx.x; i < nparts; i += 256) s += (double)partial[i];
    sd[threadIdx.x] = s;
    __syncthreads();
    for (int d = 128; d > 0; d >>= 1) {
        if (threadIdx.x < d) sd[threadIdx.x] += sd[threadIdx.x + d];
        __syncthreads();
    }
    if (threadIdx.x == 0) out[0] = (float)(sd[0] * inv_n);
}

extern "C" void kernel_launch(void* const* d_in, const int* in_sizes, int n_in,
                              void* d_out, int out_size, void* d_ws, size_t ws_size,
                              hipStream_t stream)
{
    const float* pred = (const float*)d_in[0];
    const float* targ = (const float*)d_in[1];
    const int n = in_sizes[0];
    const int rows = n / TLEN;   // 16

    const double csd = 1.0 - exp(-2200.0 / (50.0 * 44100.0));
    const double cld = 1.0 - exp(-2200.0 / (3000.0 * 44100.0));
    const double amSd = 1.0 - csd, amLd = 1.0 - cld;
    const float amS = (float)amSd, amL = (float)amLd;
    const float Ac16S = (float)pow(amSd, 16.0);
    const float Ac16L = (float)pow(amLd, 16.0);
    const float AcTS  = (float)pow(amSd, 1024.0);   // per 64-seg tile
    const float AcTL  = (float)pow(amLd, 1024.0);

    // ws: [0,1024) ctrl ints; pB (NEMA*rows*SEGS f = 16.8 MB);
    // tA, tC (NEMA*rows*NTIL f = 256 KB each); partial (rows*LPR f).
    char* wsb = (char*)d_ws;
    int* ctrl      = (int*)wsb;
    float* pB      = (float*)(wsb + 1024);
    float* tA      = pB + (size_t)NEMA * rows * SEGS;
    float* tC      = tA + (size_t)NEMA * rows * NTIL;
    float* partial = tC + (size_t)NEMA * rows * NTIL;

    hipMemsetAsync(ctrl, 0, (2 + 2 * rows) * sizeof(int), stream);

    ldr_mega<<<1024, TPB, 0, stream>>>(pred, targ, pB, tA, tC, partial, ctrl,
                                       amS, amL, Ac16S, Ac16L, AcTS, AcTL, rows);

    const double inv_n = 1.0 / ((double)rows * (double)TLEN);
    ldr_finalize<<<1, 256, 0, stream>>>(partial, rows * LPR, (float*)d_out, inv_n);
}

// Round 17
// 75.506 us; speedup vs baseline: 24.2493x; 24.2493x over previous
//
#include <hip/hip_runtime.h>
#include <math.h>

#define TPB   256
#define SL    16             // per-segment length
#define SEGS  65536          // segments per row
#define TLEN  1048576
#define MOFF  4065           // 65047 / 16
#define ROFF  7              // 65047 % 16
#define NEMA  4              // 0: short/pred, 1: short/targ, 2: long/pred, 3: long/targ
#define TPL   256            // 256-seg tiles per row

typedef float v4f __attribute__((ext_vector_type(4)));

__device__ __forceinline__ float comp(const float4& v, int m) {
    return m == 0 ? v.x : m == 1 ? v.y : m == 2 ? v.z : v.w;
}

__device__ __forceinline__ float ipowf(float base, int e) {
    float r = 1.0f, p = base;
    while (e) { if (e & 1) r *= p; p *= p; e >>= 1; }
    return r;
}

// Pass 1 (v3): ONE segment per thread — exactly the loss kernel's geometry
// (1M threads, 4096 blocks) and per-stream access pattern (lane stride 64B,
// 4 sequential float4 loads per stream), with all 8 loads batched in one
// inline-asm block (R14's proven MLP mechanism). Block = one 256-seg tile;
// tile aggregate via weighted wave reduce + 4-slot LDS combine.
__global__ __launch_bounds__(TPB) void ldr_partials(
    const float* __restrict__ pred, const float* __restrict__ targ,
    float amS, float amL, float Ac16S, float Ac16L,
    float* __restrict__ pB, float* __restrict__ tA, int rows)
{
    __shared__ float wt[4][NEMA];
    const int bgl = blockIdx.x;
    const int r = bgl >> 8, tile = bgl & 255;
    const int j = threadIdx.x, lane = j & 63, w = j >> 6;
    const int m = tile * 256 + j;                  // row-local segment
    const size_t base = (size_t)r * TLEN + (size_t)m * SL;
    const float* P = pred + base;
    const float* T = targ + base;

    v4f u0, u1, u2, u3, w0, w1, w2, w3;
    asm volatile(
        "global_load_dwordx4 %[u0], %[pa], off\n\t"
        "global_load_dwordx4 %[u1], %[pa], off offset:16\n\t"
        "global_load_dwordx4 %[u2], %[pa], off offset:32\n\t"
        "global_load_dwordx4 %[u3], %[pa], off offset:48\n\t"
        "global_load_dwordx4 %[w0], %[ta], off\n\t"
        "global_load_dwordx4 %[w1], %[ta], off offset:16\n\t"
        "global_load_dwordx4 %[w2], %[ta], off offset:32\n\t"
        "global_load_dwordx4 %[w3], %[ta], off offset:48\n\t"
        "s_waitcnt vmcnt(0)"
        : [u0] "=&v"(u0), [u1] "=&v"(u1), [u2] "=&v"(u2), [u3] "=&v"(u3),
          [w0] "=&v"(w0), [w1] "=&v"(w1), [w2] "=&v"(w2), [w3] "=&v"(w3)
        : [pa] "v"(P), [ta] "v"(T)
        : "memory");

    float sp = 0.f, st = 0.f, lp = 0.f, lt = 0.f;
    #define PQ(Q) { sp = fmaf(amS, sp, Q.x); lp = fmaf(amL, lp, Q.x);         \
                    sp = fmaf(amS, sp, Q.y); lp = fmaf(amL, lp, Q.y);         \
                    sp = fmaf(amS, sp, Q.z); lp = fmaf(amL, lp, Q.z);         \
                    sp = fmaf(amS, sp, Q.w); lp = fmaf(amL, lp, Q.w); }
    #define TQ(Q) { st = fmaf(amS, st, Q.x); lt = fmaf(amL, lt, Q.x);         \
                    st = fmaf(amS, st, Q.y); lt = fmaf(amL, lt, Q.y);         \
                    st = fmaf(amS, st, Q.z); lt = fmaf(amL, lt, Q.z);         \
                    st = fmaf(amS, st, Q.w); lt = fmaf(amL, lt, Q.w); }
    PQ(u0) PQ(u1) PQ(u2) PQ(u3)
    TQ(w0) TQ(w1) TQ(w2) TQ(w3)
    #undef PQ
    #undef TQ

    const size_t plane = (size_t)rows * SEGS;
    const size_t idx = (size_t)r * SEGS + m;
    pB[0 * plane + idx] = sp;
    pB[1 * plane + idx] = st;
    pB[2 * plane + idx] = lp;
    pB[3 * plane + idx] = lt;

    // tile aggregate: T = sum_j agg_j * Ac16^(255-j); per-wave weighted
    // reduce with Ac16^(63-lane), cross-wave combine with A64 = Ac16^64.
    const float wgtS = ipowf(Ac16S, 63 - lane);
    const float wgtL = ipowf(Ac16L, 63 - lane);
    float vals[NEMA] = { sp * wgtS, st * wgtS, lp * wgtL, lt * wgtL };
    #pragma unroll
    for (int E = 0; E < NEMA; ++E) {
        float s = vals[E];
        #pragma unroll
        for (int d = 32; d > 0; d >>= 1) s += __shfl_xor(s, d, 64);
        if (lane == 0) wt[w][E] = s;
    }
    __syncthreads();
    if (j == 0) {
        const float A64S = ipowf(Ac16S, 64), A64L = ipowf(Ac16L, 64);
        #pragma unroll
        for (int E = 0; E < NEMA; ++E) {
            const float A64 = (E < 2) ? A64S : A64L;
            float t = wt[0][E];
            t = fmaf(A64, t, wt[1][E]);
            t = fmaf(A64, t, wt[2][E]);
            t = fmaf(A64, t, wt[3][E]);
            tA[((size_t)E * rows + r) * TPL + tile] = t;
        }
    }
}

// Pass 2: scan 256 tile aggregates per plane -> tile carry-ins. (R15 verified)
__global__ __launch_bounds__(64) void ldr_tile_scan(
    const float* __restrict__ tA, float* __restrict__ tC,
    float AcT_S, float AcT_L, int rows)
{
    const int g = blockIdx.x, lane = threadIdx.x;
    const float AcT = (g < 2 * rows) ? AcT_S : AcT_L;    // am^4096 per tile
    const float AcT4 = ((AcT * AcT) * (AcT * AcT));
    const float* Bv = tA + (size_t)g * TPL + lane * 4;
    float b4[4];
    float B = 0.f;
    #pragma unroll
    for (int m = 0; m < 4; ++m) { b4[m] = Bv[m]; B = fmaf(AcT, B, b4[m]); }
    float incl = B, Ad = AcT4;
    #pragma unroll
    for (int d = 1; d < 64; d <<= 1) {
        float pb = __shfl_up(incl, d, 64);
        if (lane >= d) incl = fmaf(Ad, pb, incl);
        Ad *= Ad;
    }
    float carry = __shfl_up(incl, 1, 64);
    if (lane == 0) carry = 0.f;
    float* co = tC + (size_t)g * TPL + lane * 4;
    #pragma unroll
    for (int m = 0; m < 4; ++m) {
        co[m] = carry;
        carry = fmaf(AcT, carry, b4[m]);
    }
}

// Pass 3: fused loss (R15 verified, unchanged).
__global__ __launch_bounds__(TPB) void ldr_loss(
    const float* __restrict__ pred, const float* __restrict__ targ,
    const float* __restrict__ pB, const float* __restrict__ tC,
    float amS, float amL, float Ac16S, float Ac16L,
    float* __restrict__ partial, int rows)
{
    __shared__ float sS[2][4], sL[2][4];
    __shared__ float longC[2][512];
    __shared__ float rs[4];
    const int bgl = blockIdx.x;
    const int r = bgl >> 8, bl = bgl & 255;
    const int j = threadIdx.x, lane = j & 63, w = j >> 6;
    const int m = bl * 256 + j;
    const size_t plane = (size_t)rows * SEGS;
    const size_t rbase = (size_t)r * SEGS;

    const float A1024S = ipowf(Ac16S, 64);
    const float aLaneS = ipowf(Ac16S, lane);
    float aggS[2];
    aggS[0] = pB[0 * plane + rbase + m];
    aggS[1] = pB[1 * plane + rbase + m];
    float inS0 = aggS[0], inS1 = aggS[1], Ad = Ac16S;
    #pragma unroll
    for (int d = 1; d < 64; d <<= 1) {
        float p0 = __shfl_up(inS0, d, 64);
        float p1 = __shfl_up(inS1, d, 64);
        if (lane >= d) { inS0 = fmaf(Ad, p0, inS0); inS1 = fmaf(Ad, p1, inS1); }
        Ad *= Ad;
    }
    float exS0 = __shfl_up(inS0, 1, 64), exS1 = __shfl_up(inS1, 1, 64);
    if (lane == 0) { exS0 = 0.f; exS1 = 0.f; }
    if (lane == 63) { sS[0][w] = inS0; sS[1][w] = inS1; }

    const int half = j >> 7;
    const int hh = j & 127;
    const int tsel = (bl + 15 + half) & 255;
    const float Ac32L = Ac16L * Ac16L;
    const float A2048L = ipowf(Ac32L, 64);
    const float aLaneL = ipowf(Ac32L, lane);
    float2 agL0 = *(const float2*)(pB + 2 * plane + rbase + tsel * 256 + 2 * hh);
    float2 agL1 = *(const float2*)(pB + 3 * plane + rbase + tsel * 256 + 2 * hh);
    float pa0 = fmaf(Ac16L, agL0.x, agL0.y);
    float pa1 = fmaf(Ac16L, agL1.x, agL1.y);
    float inL0 = pa0, inL1 = pa1;
    Ad = Ac32L;
    #pragma unroll
    for (int d = 1; d < 64; d <<= 1) {
        float p0 = __shfl_up(inL0, d, 64);
        float p1 = __shfl_up(inL1, d, 64);
        if (lane >= d) { inL0 = fmaf(Ad, p0, inL0); inL1 = fmaf(Ad, p1, inL1); }
        Ad *= Ad;
    }
    float exL0 = __shfl_up(inL0, 1, 64), exL1 = __shfl_up(inL1, 1, 64);
    if (lane == 0) { exL0 = 0.f; exL1 = 0.f; }
    if (lane == 63) { sL[0][w] = inL0; sL[1][w] = inL1; }
    __syncthreads();

    {
        const float baseS0 = tC[((size_t)0 * rows + r) * TPL + bl];
        const float baseS1 = tC[((size_t)1 * rows + r) * TPL + bl];
        float Wc0 = 0.f, Wc1 = 0.f;
        for (int u = 0; u < w; ++u) {
            Wc0 = fmaf(Wc0, A1024S, sS[0][u]);
            Wc1 = fmaf(Wc1, A1024S, sS[1][u]);
        }
        const float aThS = aLaneS * ipowf(A1024S, w);
        exS0 = fmaf(aThS, baseS0, fmaf(aLaneS, Wc0, exS0));
        exS1 = fmaf(aThS, baseS1, fmaf(aLaneS, Wc1, exS1));
    }
    {
        const float baseL0 = tC[((size_t)2 * rows + r) * TPL + tsel];
        const float baseL1 = tC[((size_t)3 * rows + r) * TPL + tsel];
        const int hw = w & 1, fw = w & 2;
        float Wc0 = hw ? sL[0][fw] : 0.f;
        float Wc1 = hw ? sL[1][fw] : 0.f;
        const float aThL = aLaneL * (hw ? A2048L : 1.f);
        float c00 = fmaf(aThL, baseL0, fmaf(aLaneL, Wc0, exL0));
        float c10 = fmaf(aThL, baseL1, fmaf(aLaneL, Wc1, exL1));
        const int i0 = half * 256 + 2 * hh;
        longC[0][i0] = c00; longC[0][i0 + 1] = fmaf(Ac16L, c00, agL0.x);
        longC[1][i0] = c10; longC[1][i0 + 1] = fmaf(Ac16L, c10, agL1.x);
    }
    __syncthreads();
    const float cSp = exS0, cSt = exS1;
    const float cLp = longC[0][225 + j];
    const float cLt = longC[1][225 + j];

    const int a = (m + MOFF) & (SEGS - 1);
    const int bseg = (m + MOFF + 1) & (SEGS - 1);
    const float* P = pred + (size_t)r * TLEN;
    const float* T = targ + (size_t)r * TLEN;

    float sp[SL], st[SL];
    {
        const float4* Sp4 = (const float4*)(P + (size_t)m * SL);
        const float4* St4 = (const float4*)(T + (size_t)m * SL);
        float ysp = cSp, yst = cSt;
        #pragma unroll
        for (int q = 0; q < SL / 4; ++q) {
            float4 u = Sp4[q], v = St4[q];
            #pragma unroll
            for (int mm = 0; mm < 4; ++mm) {
                ysp = fmaf(amS, ysp, comp(u, mm)); sp[4 * q + mm] = ysp;
                yst = fmaf(amS, yst, comp(v, mm)); st[4 * q + mm] = yst;
            }
        }
    }
    float ylp = cLp, ylt = cLt;
    const float4* Ap4 = (const float4*)(P + (size_t)a * SL);
    const float4* At4 = (const float4*)(T + (size_t)a * SL);
    const float4* Bp4 = (const float4*)(P + (size_t)bseg * SL);
    const float4* Bt4 = (const float4*)(T + (size_t)bseg * SL);

    float lsum = 0.f;
    #pragma unroll
    for (int q = 0; q < SL / 4; ++q) {
        float4 u = Ap4[q], v = At4[q];
        #pragma unroll
        for (int mm = 0; mm < 4; ++mm) {
            const int e = 4 * q + mm;
            ylp = fmaf(amL, ylp, comp(u, mm));
            ylt = fmaf(amL, ylt, comp(v, mm));
            if (e >= ROFF) {
                const int i = e - ROFF;
                lsum += fabsf(__logf(__fdividef(sp[i] * ylt, st[i] * ylp)));
            }
        }
    }
    #pragma unroll
    for (int q = 0; q < 2; ++q) {
        float4 u = Bp4[q], v = Bt4[q];
        #pragma unroll
        for (int mm = 0; mm < 4; ++mm) {
            const int e = 4 * q + mm;
            if (e < ROFF) {
                ylp = fmaf(amL, ylp, comp(u, mm));
                ylt = fmaf(amL, ylt, comp(v, mm));
                const int i = e + (SL - ROFF);
                lsum += fabsf(__logf(__fdividef(sp[i] * ylt, st[i] * ylp)));
            }
        }
    }

    #pragma unroll
    for (int d = 32; d > 0; d >>= 1) lsum += __shfl_xor(lsum, d, 64);
    if (lane == 0) rs[w] = lsum;
    __syncthreads();
    if (j == 0) partial[bgl] = rs[0] + rs[1] + rs[2] + rs[3];
}

__global__ void ldr_finalize(const float* __restrict__ partial, int nparts,
                             float* __restrict__ out, double inv_n)
{
    __shared__ double sd[256];
    double s = 0.0;
    for (int i = threadIdx.x; i < nparts; i += 256) s += (double)partial[i];
    sd[threadIdx.x] = s;
    __syncthreads();
    for (int d = 128; d > 0; d >>= 1) {
        if (threadIdx.x < d) sd[threadIdx.x] += sd[threadIdx.x + d];
        __syncthreads();
    }
    if (threadIdx.x == 0) out[0] = (float)(sd[0] * inv_n);
}

extern "C" void kernel_launch(void* const* d_in, const int* in_sizes, int n_in,
                              void* d_out, int out_size, void* d_ws, size_t ws_size,
                              hipStream_t stream)
{
    const float* pred = (const float*)d_in[0];
    const float* targ = (const float*)d_in[1];
    const int n = in_sizes[0];
    const int rows = n / TLEN;   // 16

    const double csd = 1.0 - exp(-2200.0 / (50.0 * 44100.0));
    const double cld = 1.0 - exp(-2200.0 / (3000.0 * 44100.0));
    const double amSd = 1.0 - csd, amLd = 1.0 - cld;
    const float amS = (float)amSd, amL = (float)amLd;
    const float Ac16S = (float)pow(amSd, 16.0);
    const float Ac16L = (float)pow(amLd, 16.0);
    const float AcT_S = (float)pow(amSd, 4096.0);   // per 256-seg tile
    const float AcT_L = (float)pow(amLd, 4096.0);

    // ws: [0,256) reserved; pB (NEMA*rows*SEGS f = 16.8 MB); tA, tC
    // (NEMA*rows*TPL f = 64 KB each); partial (4096 f).
    char* wsb = (char*)d_ws;
    float* pB      = (float*)(wsb + 256);
    float* tA      = pB + (size_t)NEMA * rows * SEGS;
    float* tC      = tA + (size_t)NEMA * rows * TPL;
    float* partial = tC + (size_t)NEMA * rows * TPL;

    const int nblocks = rows * TPL;                // 4096
    const int nplanes = NEMA * rows;               // 64

    ldr_partials<<<nblocks, TPB, 0, stream>>>(pred, targ, amS, amL,
                                              Ac16S, Ac16L, pB, tA, rows);
    ldr_tile_scan<<<nplanes, 64, 0, stream>>>(tA, tC, AcT_S, AcT_L, rows);
    ldr_loss<<<nblocks, TPB, 0, stream>>>(pred, targ, pB, tC, amS, amL,
                                          Ac16S, Ac16L, partial, rows);

    const double inv_n = 1.0 / ((double)rows * (double)TLEN);
    ldr_finalize<<<1, 256, 0, stream>>>(partial, nblocks, (float*)d_out, inv_n);
}